// Round 1
// 625.474 us; speedup vs baseline: 3.1777x; 3.1777x over previous
//
#include <hip/hip_runtime.h>
#include <stdint.h>

// out[m,n] = -sqrt( ||A[m]||^2 + ||B[n]||^2 - 2*A[m].B[n] )
// A = features [M=16384, K=2048], B = prototypes [N=1000, K=2048].
// MFMA build: cross-term via split-bf16 (hi+lo) 3-pass mfma_f32_16x16x32_bf16,
// norms precomputed in workspace. Falls back to the previous verified VALU
// kernel if the workspace is too small. Input dtype (fp32 vs bf16) sniffed
// on-device as before; output fp32.

#define KDIM 2048
#define BM 128
#define BN 128
#define BKS 32
#define NSTEPS (KDIM / BKS)

typedef __attribute__((ext_vector_type(8))) __bf16 bf16x8;
typedef __attribute__((ext_vector_type(4))) float f32x4;

__device__ __forceinline__ bool sniff_is_f32(const void* Araw) {
  // Genuine bf16 N(0,1) data -> max |x| < 10. fp32 data -> mantissa
  // half-words give |x| > 1e4 essentially surely. Uniform across block.
  const uint16_t* sniff = (const uint16_t*)Araw;
  float mx = 0.f;
#pragma unroll
  for (int i = 0; i < 64; ++i) {
    float v = __uint_as_float(((uint32_t)sniff[i]) << 16);
    mx = fmaxf(mx, fabsf(v));
  }
  return mx > 1e4f;
}

// ---------------------------------------------------------------- norms ----
__global__ __launch_bounds__(256) void norms_kernel(
    const void* __restrict__ Araw, const void* __restrict__ Braw,
    float* __restrict__ fsq, float* __restrict__ psq, int M, int N) {
  const bool isf32 = sniff_is_f32(Araw);
  const int wave = threadIdx.x >> 6;
  const int lane = threadIdx.x & 63;
  const int row = blockIdx.x * 4 + wave;
  if (row >= M + N) return;
  const bool isA = row < M;
  const size_t r = isA ? (size_t)row : (size_t)(row - M);
  float s = 0.f;
  if (isf32) {
    const float* p = (isA ? (const float*)Araw : (const float*)Braw) + r * KDIM;
#pragma unroll
    for (int it = 0; it < KDIM / 256; ++it) {
      float4 v = *((const float4*)p + it * 64 + lane);
      s += v.x * v.x + v.y * v.y + v.z * v.z + v.w * v.w;
    }
  } else {
    const uint16_t* p =
        (isA ? (const uint16_t*)Araw : (const uint16_t*)Braw) + r * KDIM;
#pragma unroll
    for (int it = 0; it < KDIM / 256; ++it) {
      uint2 v = *((const uint2*)p + it * 64 + lane);
      float e0 = __uint_as_float(v.x << 16);
      float e1 = __uint_as_float(v.x & 0xFFFF0000u);
      float e2 = __uint_as_float(v.y << 16);
      float e3 = __uint_as_float(v.y & 0xFFFF0000u);
      s += e0 * e0 + e1 * e1 + e2 * e2 + e3 * e3;
    }
  }
#pragma unroll
  for (int o = 32; o > 0; o >>= 1) s += __shfl_down(s, o, 64);
  if (lane == 0) {
    if (isA) fsq[r] = s;
    else     psq[r] = s;
  }
}

// ----------------------------------------------------------- split pack ----
__device__ __forceinline__ uint32_t pack_hi16(uint32_t a, uint32_t b) {
  // two fp32 bit-patterns -> packed (bf16(a) low, bf16(b) high), truncation
  return (a >> 16) | (b & 0xFFFF0000u);
}

__device__ __forceinline__ void split_store(bool isf32, uint4 q0, uint4 q1,
                                            uint32_t* dst_h, uint32_t* dst_l) {
  if (isf32) {
    uint32_t u[8] = {q0.x, q0.y, q0.z, q0.w, q1.x, q1.y, q1.z, q1.w};
    uint32_t l[8];
#pragma unroll
    for (int j = 0; j < 8; ++j) {
      float hf = __uint_as_float(u[j] & 0xFFFF0000u);  // hi = truncated bf16
      l[j] = __float_as_uint(__uint_as_float(u[j]) - hf);  // exact residual
    }
    uint4 hp = {pack_hi16(u[0], u[1]), pack_hi16(u[2], u[3]),
                pack_hi16(u[4], u[5]), pack_hi16(u[6], u[7])};
    uint4 lp = {pack_hi16(l[0], l[1]), pack_hi16(l[2], l[3]),
                pack_hi16(l[4], l[5]), pack_hi16(l[6], l[7])};
    *(uint4*)dst_h = hp;
    *(uint4*)dst_l = lp;
  } else {
    *(uint4*)dst_h = q0;                  // input already bf16-packed
    *(uint4*)dst_l = make_uint4(0, 0, 0, 0);
  }
}

// ----------------------------------------------------------------- GEMM ----
__global__ __launch_bounds__(256, 2) void gemm_kernel(
    const void* __restrict__ Araw, const void* __restrict__ Braw,
    const float* __restrict__ fsq, const float* __restrict__ psq,
    float* __restrict__ out, int M, int N) {
  // 16B chunk-swizzled tiles: chunk' = chunk ^ ((row>>1)&3)  (write == read)
  __shared__ uint32_t Ah[2][BM][16];
  __shared__ uint32_t Al[2][BM][16];
  __shared__ uint32_t Bh[2][BN][16];
  __shared__ uint32_t Bl[2][BN][16];

  const bool isf32 = sniff_is_f32(Araw);
  const int tid = threadIdx.x;
  const int lane = tid & 63;
  const int wave = tid >> 6;
  const int m0 = blockIdx.y * BM;
  const int n0 = blockIdx.x * BN;

  const float* A32 = (const float*)Araw;
  const float* B32 = (const float*)Braw;
  const uint16_t* A16 = (const uint16_t*)Araw;
  const uint16_t* B16 = (const uint16_t*)Braw;

  // staging geometry: per step each thread covers rows {crow, crow+64},
  // chunk cch (8 consecutive k) for both A and B.
  const int crow = tid >> 2;  // 0..63
  const int cch = tid & 3;    // 0..3

  const int wr = wave >> 1;   // wave row (0..1): 64-row band
  const int wc = wave & 1;    // wave col (0..1): 64-col band
  const int lr = lane & 15;   // fragment row/col within 16
  const int lg = lane >> 4;   // k-group (8 elems) == LDS chunk

  uint4 qa0[2], qa1[2], qb0[2], qb1[2];

  auto load_step = [&](int ks) {
#pragma unroll
    for (int s = 0; s < 2; ++s) {
      const int row = crow + 64 * s;
      int gm = m0 + row; gm = gm < M ? gm : M - 1;
      int gn = n0 + row; gn = gn < N ? gn : N - 1;  // clamp tail rows
      const size_t ea = (size_t)gm * KDIM + ks * BKS + cch * 8;
      const size_t eb = (size_t)gn * KDIM + ks * BKS + cch * 8;
      if (isf32) {
        qa0[s] = *(const uint4*)(A32 + ea);
        qa1[s] = *(const uint4*)(A32 + ea + 4);
        qb0[s] = *(const uint4*)(B32 + eb);
        qb1[s] = *(const uint4*)(B32 + eb + 4);
      } else {
        qa0[s] = *(const uint4*)(A16 + ea);
        qb0[s] = *(const uint4*)(B16 + eb);
      }
    }
  };

  auto store_step = [&](int b) {
#pragma unroll
    for (int s = 0; s < 2; ++s) {
      const int row = crow + 64 * s;
      const int pc = cch ^ ((row >> 1) & 3);
      split_store(isf32, qa0[s], qa1[s], &Ah[b][row][pc * 4], &Al[b][row][pc * 4]);
      split_store(isf32, qb0[s], qb1[s], &Bh[b][row][pc * 4], &Bl[b][row][pc * 4]);
    }
  };

  f32x4 acc[4][4] = {};

  load_step(0);
  store_step(0);
  __syncthreads();

  for (int ks = 0; ks < NSTEPS; ++ks) {
    const int buf = ks & 1;
    const int nxt = ks + 1;
    if (nxt < NSTEPS) load_step(nxt);  // issue early: hides under MFMA

    bf16x8 ah[4], al[4], bh[4], bl[4];
#pragma unroll
    for (int i = 0; i < 4; ++i) {
      const int r = wr * 64 + i * 16 + lr;
      const int pc = lg ^ ((r >> 1) & 3);
      ah[i] = *(const bf16x8*)&Ah[buf][r][pc * 4];
      al[i] = *(const bf16x8*)&Al[buf][r][pc * 4];
    }
#pragma unroll
    for (int j = 0; j < 4; ++j) {
      const int r = wc * 64 + j * 16 + lr;
      const int pc = lg ^ ((r >> 1) & 3);
      bh[j] = *(const bf16x8*)&Bh[buf][r][pc * 4];
      bl[j] = *(const bf16x8*)&Bl[buf][r][pc * 4];
    }

#pragma unroll
    for (int i = 0; i < 4; ++i)
#pragma unroll
      for (int j = 0; j < 4; ++j) {
        acc[i][j] = __builtin_amdgcn_mfma_f32_16x16x32_bf16(ah[i], bh[j], acc[i][j], 0, 0, 0);
        acc[i][j] = __builtin_amdgcn_mfma_f32_16x16x32_bf16(ah[i], bl[j], acc[i][j], 0, 0, 0);
        acc[i][j] = __builtin_amdgcn_mfma_f32_16x16x32_bf16(al[i], bh[j], acc[i][j], 0, 0, 0);
      }

    if (nxt < NSTEPS) store_step(nxt & 1);
    __syncthreads();
  }

  // Epilogue: C/D layout col=lane&15, row=(lane>>4)*4+reg (m89-verified).
#pragma unroll
  for (int j = 0; j < 4; ++j) {
    const int n = n0 + wc * 64 + j * 16 + lr;
    if (n >= N) continue;
    const float pn = psq[n];
#pragma unroll
    for (int i = 0; i < 4; ++i) {
      const int mb = m0 + wr * 64 + i * 16 + lg * 4;
#pragma unroll
      for (int r = 0; r < 4; ++r) {
        const int m = mb + r;
        if (m < M) {
          const float d2 = fsq[m] + pn - 2.f * acc[i][j][r];
          out[(size_t)m * N + n] = -sqrtf(fmaxf(d2, 0.f));
        }
      }
    }
  }
}

// ----------------------------------------------- fallback (prev verified) ----
#define TILE 64
#define FBK 32

__global__ __launch_bounds__(256) void dist_kernel(
    const void* __restrict__ Araw, const void* __restrict__ Braw,
    float* __restrict__ out, int M, int N) {
  __shared__ float Af[TILE][FBK + 1];
  __shared__ float Bf[TILE][FBK + 1];

  const int tid = threadIdx.x;
  const int m0 = blockIdx.y * TILE;
  const int n0 = blockIdx.x * TILE;

  const bool isf32 = sniff_is_f32(Araw);

  const float* A32 = (const float*)Araw;
  const float* B32 = (const float*)Braw;
  const uint16_t* A16 = (const uint16_t*)Araw;
  const uint16_t* B16 = (const uint16_t*)Braw;

  const int ty = tid >> 4;
  const int tx = tid & 15;

  float acc[4][4] = {};

  for (int k0 = 0; k0 < KDIM; k0 += FBK) {
#pragma unroll
    for (int i = 0; i < 8; ++i) {
      const int f = i * 256 + tid;
      const int r = f >> 5;
      const int c = f & 31;
      const size_t ka = (size_t)(m0 + r) * KDIM + (k0 + c);
      int rb = n0 + r;
      rb = rb < N ? rb : N - 1;
      const size_t kb = (size_t)rb * KDIM + (k0 + c);
      float av, bv;
      if (isf32) {
        av = A32[ka];
        bv = B32[kb];
      } else {
        av = __uint_as_float(((uint32_t)A16[ka]) << 16);
        bv = __uint_as_float(((uint32_t)B16[kb]) << 16);
      }
      Af[r][c] = av;
      Bf[r][c] = bv;
    }
    __syncthreads();

#pragma unroll 4
    for (int kk = 0; kk < FBK; ++kk) {
      float a[4], b[4];
#pragma unroll
      for (int i = 0; i < 4; ++i) a[i] = Af[ty * 4 + i][kk];
#pragma unroll
      for (int j = 0; j < 4; ++j) b[j] = Bf[tx * 4 + j][kk];
#pragma unroll
      for (int i = 0; i < 4; ++i)
#pragma unroll
        for (int j = 0; j < 4; ++j) {
          const float d = a[i] - b[j];
          acc[i][j] = fmaf(d, d, acc[i][j]);
        }
    }
    __syncthreads();
  }

#pragma unroll
  for (int i = 0; i < 4; ++i) {
    const int m = m0 + ty * 4 + i;
#pragma unroll
    for (int j = 0; j < 4; ++j) {
      const int n = n0 + tx * 4 + j;
      if (m < M && n < N) out[(size_t)m * N + n] = -sqrtf(acc[i][j]);
    }
  }
}

// -------------------------------------------------------------- launcher ----
extern "C" void kernel_launch(void* const* d_in, const int* in_sizes, int n_in,
                              void* d_out, int out_size, void* d_ws,
                              size_t ws_size, hipStream_t stream) {
  (void)n_in; (void)out_size;
  const void* feat = d_in[0];
  const void* prot = d_in[1];
  float* out = (float*)d_out;

  const int M = in_sizes[0] / KDIM;  // 16384 (element counts, dtype-free)
  const int N = in_sizes[1] / KDIM;  // 1000

  const size_t ws_need = (size_t)(M + N) * sizeof(float);
  if (d_ws != nullptr && ws_size >= ws_need) {
    float* fsq = (float*)d_ws;
    float* psq = fsq + M;
    const int rows = M + N;
    norms_kernel<<<dim3((rows + 3) / 4), dim3(256), 0, stream>>>(
        feat, prot, fsq, psq, M, N);
    dim3 grid((N + BN - 1) / BN, (M + BM - 1) / BM);
    gemm_kernel<<<grid, dim3(256), 0, stream>>>(feat, prot, fsq, psq, out, M, N);
  } else {
    dim3 grid((N + TILE - 1) / TILE, (M + TILE - 1) / TILE);
    dist_kernel<<<grid, dim3(256), 0, stream>>>(feat, prot, out, M, N);
  }
}

// Round 2
// 625.249 us; speedup vs baseline: 3.1788x; 1.0004x over previous
//
#include <hip/hip_runtime.h>
#include <stdint.h>

// out[m,n] = -sqrt( ||A[m]||^2 + ||B[n]||^2 - 2*A[m].B[n] )
// A = features [M=16384, K=2048], B = prototypes [N=1000, K=2048].
// Single fused kernel:
//  * cross-term: 1-pass bf16 MFMA (round-to-nearest conversion). Error in d
//    is ~5e-3 worst case vs 0.5 tolerance (min pairwise distance ~60, norms
//    kept exact fp32).
//  * row norms computed on the fly from the fp32 staging registers,
//    shfl-reduced across the 4 chunk-lanes, parked in LDS for the epilogue.
//  * LDS tiles [128][16 u32] with chunk swizzle pc = cch ^ ((row>>1)&3)
//    (identical to round-1 layout: measured 0 bank conflicts).
//  * input dtype (fp32 vs bf16) sniffed on-device; output fp32.

#define KDIM 2048
#define BM 128
#define BN 128
#define BKS 32
#define NSTEPS (KDIM / BKS)

typedef __attribute__((ext_vector_type(8))) __bf16 bf16x8;
typedef __attribute__((ext_vector_type(4))) float f32x4;

__device__ __forceinline__ bool sniff_is_f32(const void* Araw) {
  // bf16 N(0,1) data -> max |x| < 10; fp32 data -> mantissa half-words give
  // |x| > 1e4 essentially surely. Uniform across all blocks/lanes.
  const uint16_t* sniff = (const uint16_t*)Araw;
  float mx = 0.f;
#pragma unroll
  for (int i = 0; i < 64; ++i) {
    float v = __uint_as_float(((uint32_t)sniff[i]) << 16);
    mx = fmaxf(mx, fabsf(v));
  }
  return mx > 1e4f;
}

__device__ __forceinline__ uint32_t bf16rn(uint32_t u) {
  // fp32 bits -> bf16 bits, round-to-nearest-even (finite inputs only)
  return (u + 0x7FFFu + ((u >> 16) & 1u)) >> 16;
}
__device__ __forceinline__ uint32_t pack_rn(uint32_t a, uint32_t b) {
  return bf16rn(a) | (bf16rn(b) << 16);
}

__global__ __launch_bounds__(256) void dist_mfma_kernel(
    const void* __restrict__ Araw, const void* __restrict__ Braw,
    float* __restrict__ out, int M, int N) {
  __shared__ uint32_t Ab[2][BM][16];   // [buf][row][16 u32 = 32 bf16]
  __shared__ uint32_t Bb[2][BN][16];
  __shared__ float fsqs[BM];
  __shared__ float psqs[BN];

  const bool isf32 = sniff_is_f32(Araw);
  const int tid = threadIdx.x;
  const int lane = tid & 63;
  const int wave = tid >> 6;
  const int m0 = blockIdx.y * BM;
  const int n0 = blockIdx.x * BN;

  const float* A32 = (const float*)Araw;
  const float* B32 = (const float*)Braw;
  const uint16_t* A16 = (const uint16_t*)Araw;
  const uint16_t* B16 = (const uint16_t*)Braw;

  // staging geometry: thread covers rows {crow, crow+64}, k-chunk cch (8 k)
  const int crow = tid >> 2;  // 0..63
  const int cch = tid & 3;    // 0..3

  const int wr = wave >> 1;   // wave row band (0..1) -> 64 rows
  const int wc = wave & 1;    // wave col band (0..1) -> 64 cols
  const int lr = lane & 15;   // fragment row/col within 16
  const int lg = lane >> 4;   // k-group == LDS chunk

  uint4 qa0[2], qa1[2], qb0[2], qb1[2];
  float na[2] = {0.f, 0.f};   // running ||A-row||^2 partials (this thread's 8k slice)
  float nb[2] = {0.f, 0.f};

  auto load_step = [&](int ks) {
#pragma unroll
    for (int s = 0; s < 2; ++s) {
      const int row = crow + 64 * s;
      int gm = m0 + row; gm = gm < M ? gm : M - 1;
      int gn = n0 + row; gn = gn < N ? gn : N - 1;  // clamp tail rows
      const size_t ea = (size_t)gm * KDIM + ks * BKS + cch * 8;
      const size_t eb = (size_t)gn * KDIM + ks * BKS + cch * 8;
      if (isf32) {
        qa0[s] = *(const uint4*)(A32 + ea);
        qa1[s] = *(const uint4*)(A32 + ea + 4);
        qb0[s] = *(const uint4*)(B32 + eb);
        qb1[s] = *(const uint4*)(B32 + eb + 4);
      } else {
        qa0[s] = *(const uint4*)(A16 + ea);
        qb0[s] = *(const uint4*)(B16 + eb);
      }
    }
  };

  auto store_step = [&](int b) {
#pragma unroll
    for (int s = 0; s < 2; ++s) {
      const int row = crow + 64 * s;
      const int pc = (cch ^ ((row >> 1) & 3)) * 4;
      if (isf32) {
        const uint32_t ua[8] = {qa0[s].x, qa0[s].y, qa0[s].z, qa0[s].w,
                                qa1[s].x, qa1[s].y, qa1[s].z, qa1[s].w};
        const uint32_t ub[8] = {qb0[s].x, qb0[s].y, qb0[s].z, qb0[s].w,
                                qb1[s].x, qb1[s].y, qb1[s].z, qb1[s].w};
        float sa = 0.f, sb = 0.f;
#pragma unroll
        for (int j = 0; j < 8; ++j) {
          const float fa = __uint_as_float(ua[j]);
          const float fb = __uint_as_float(ub[j]);
          sa = fmaf(fa, fa, sa);
          sb = fmaf(fb, fb, sb);
        }
        na[s] += sa;
        nb[s] += sb;
        uint4 pa = {pack_rn(ua[0], ua[1]), pack_rn(ua[2], ua[3]),
                    pack_rn(ua[4], ua[5]), pack_rn(ua[6], ua[7])};
        uint4 pb = {pack_rn(ub[0], ub[1]), pack_rn(ub[2], ub[3]),
                    pack_rn(ub[4], ub[5]), pack_rn(ub[6], ub[7])};
        *(uint4*)&Ab[b][row][pc] = pa;
        *(uint4*)&Bb[b][row][pc] = pb;
      } else {
        const uint32_t va[4] = {qa0[s].x, qa0[s].y, qa0[s].z, qa0[s].w};
        const uint32_t vb[4] = {qb0[s].x, qb0[s].y, qb0[s].z, qb0[s].w};
        float sa = 0.f, sb = 0.f;
#pragma unroll
        for (int j = 0; j < 4; ++j) {
          const float a0 = __uint_as_float(va[j] << 16);
          const float a1 = __uint_as_float(va[j] & 0xFFFF0000u);
          const float b0 = __uint_as_float(vb[j] << 16);
          const float b1 = __uint_as_float(vb[j] & 0xFFFF0000u);
          sa = fmaf(a0, a0, fmaf(a1, a1, sa));
          sb = fmaf(b0, b0, fmaf(b1, b1, sb));
        }
        na[s] += sa;
        nb[s] += sb;
        *(uint4*)&Ab[b][row][pc] = qa0[s];
        *(uint4*)&Bb[b][row][pc] = qb0[s];
      }
    }
  };

  f32x4 acc[4][4] = {};

  load_step(0);
  store_step(0);
  __syncthreads();

  for (int ks = 0; ks < NSTEPS; ++ks) {
    const int buf = ks & 1;
    const int nxt = ks + 1;
    if (nxt < NSTEPS) load_step(nxt);  // issue early: hides under MFMA

    bf16x8 ah[4], bh[4];
#pragma unroll
    for (int i = 0; i < 4; ++i) {
      const int r = wr * 64 + i * 16 + lr;
      const int pc = (lg ^ ((r >> 1) & 3)) * 4;
      ah[i] = *(const bf16x8*)&Ab[buf][r][pc];
    }
#pragma unroll
    for (int j = 0; j < 4; ++j) {
      const int r = wc * 64 + j * 16 + lr;
      const int pc = (lg ^ ((r >> 1) & 3)) * 4;
      bh[j] = *(const bf16x8*)&Bb[buf][r][pc];
    }

#pragma unroll
    for (int i = 0; i < 4; ++i)
#pragma unroll
      for (int j = 0; j < 4; ++j)
        acc[i][j] =
            __builtin_amdgcn_mfma_f32_16x16x32_bf16(ah[i], bh[j], acc[i][j], 0, 0, 0);

    if (nxt < NSTEPS) store_step(nxt & 1);
    __syncthreads();
  }

  // ---- finalize norms: reduce the 4 k-chunk lanes (tid^1, tid^2 in-wave) ----
  float v0 = na[0], v1 = na[1], w0 = nb[0], w1 = nb[1];
#pragma unroll
  for (int o = 1; o <= 2; o <<= 1) {
    v0 += __shfl_xor(v0, o);
    v1 += __shfl_xor(v1, o);
    w0 += __shfl_xor(w0, o);
    w1 += __shfl_xor(w1, o);
  }
  if (cch == 0) {
    fsqs[crow] = v0;
    fsqs[crow + 64] = v1;
    psqs[crow] = w0;
    psqs[crow + 64] = w1;
  }
  __syncthreads();

  // ---- epilogue: C/D layout col=lane&15, row=(lane>>4)*4+reg (verified) ----
#pragma unroll
  for (int j = 0; j < 4; ++j) {
    const int nn = wc * 64 + j * 16 + lr;
    const int n = n0 + nn;
    if (n >= N) continue;
    const float pn = psqs[nn];
#pragma unroll
    for (int i = 0; i < 4; ++i) {
      const int mb = wr * 64 + i * 16 + lg * 4;
#pragma unroll
      for (int r = 0; r < 4; ++r) {
        const int m = m0 + mb + r;
        if (m < M) {
          const float d2 = fsqs[mb + r] + pn - 2.f * acc[i][j][r];
          out[(size_t)m * N + n] = -sqrtf(fmaxf(d2, 0.f));
        }
      }
    }
  }
}

// -------------------------------------------------------------- launcher ----
extern "C" void kernel_launch(void* const* d_in, const int* in_sizes, int n_in,
                              void* d_out, int out_size, void* d_ws,
                              size_t ws_size, hipStream_t stream) {
  (void)n_in; (void)out_size; (void)d_ws; (void)ws_size;
  const void* feat = d_in[0];
  const void* prot = d_in[1];
  float* out = (float*)d_out;

  const int M = in_sizes[0] / KDIM;  // 16384 (element counts, dtype-free)
  const int N = in_sizes[1] / KDIM;  // 1000

  dim3 grid((N + BN - 1) / BN, (M + BM - 1) / BM);
  dist_mfma_kernel<<<grid, dim3(256), 0, stream>>>(feat, prot, out, M, N);
}

// Round 3
// 349.827 us; speedup vs baseline: 5.6815x; 1.7873x over previous
//
#include <hip/hip_runtime.h>
#include <stdint.h>

// out[m,n] = -sqrt( ||A[m]||^2 + ||B[n]||^2 - 2*A[m].B[n] )
// A = features [M=16384, K=2048], B = prototypes [N=1000, K=2048].
//
// Three-stage plan (ws >= 71.3 MB):
//  1. prep_kernel: fp32 -> bf16(rne) conversion of A,B into workspace, fused
//     with exact fp32 row-norm computation. (bf16 input: plain copy + norms.)
//  2. gemm_kernel: pure-bf16 m97-structure GEMM: global_load_lds width-16
//     staging (linear LDS dest + inverse-swizzled global source + swizzled
//     ds_read -- rule #21 pattern; XOR chunk swizzle measured 0 conflicts in
//     rounds 1-2), 128x128 tile, 4 waves, 16x16x32 MFMA, one barrier/K-step,
//     XCD-chunked block swizzle. Epilogue applies norms + (-sqrt).
//  3. ws too small -> round-2 verified fused kernel (correctness fallback).

#define KDIM 2048
#define BM 128
#define BN 128
#define BKS 32
#define NSTEPS (KDIM / BKS)

typedef __attribute__((ext_vector_type(8))) __bf16 bf16x8;
typedef __attribute__((ext_vector_type(4))) float f32x4;

__device__ __forceinline__ bool sniff_is_f32(const void* Araw) {
  // bf16 N(0,1) data -> max |x| < 10; fp32 data -> mantissa half-words give
  // |x| > 1e4 essentially surely. Uniform across all blocks/lanes.
  const uint16_t* sniff = (const uint16_t*)Araw;
  float mx = 0.f;
#pragma unroll
  for (int i = 0; i < 64; ++i) {
    float v = __uint_as_float(((uint32_t)sniff[i]) << 16);
    mx = fmaxf(mx, fabsf(v));
  }
  return mx > 1e4f;
}

__device__ __forceinline__ uint32_t bf16rn(uint32_t u) {
  // fp32 bits -> bf16 bits, round-to-nearest-even (finite inputs only)
  return (u + 0x7FFFu + ((u >> 16) & 1u)) >> 16;
}
__device__ __forceinline__ uint32_t pack_rn(uint32_t a, uint32_t b) {
  return bf16rn(a) | (bf16rn(b) << 16);
}

__device__ __forceinline__ void gload_lds16(const void* g, void* l) {
  // async 16B global -> LDS; dest = wave-uniform base + lane*16
  __builtin_amdgcn_global_load_lds(
      (const __attribute__((address_space(1))) void*)g,
      (__attribute__((address_space(3))) void*)l, 16, 0, 0);
}

// ----------------------------------------------------- prepass: cvt+norms ----
// one wave per row; 4 rows per 256-thread block
__global__ __launch_bounds__(256) void prep_kernel(
    const void* __restrict__ Araw, const void* __restrict__ Braw,
    uint16_t* __restrict__ Abf, uint16_t* __restrict__ Bbf,
    float* __restrict__ fsq, float* __restrict__ psq, int M, int N) {
  const bool isf32 = sniff_is_f32(Araw);
  const int wave = threadIdx.x >> 6;
  const int lane = threadIdx.x & 63;
  const int row = blockIdx.x * 4 + wave;
  if (row >= M + N) return;
  const bool isA = row < M;
  const size_t r = isA ? (size_t)row : (size_t)(row - M);
  uint2* dst = (uint2*)((isA ? Abf : Bbf) + r * KDIM);
  float s = 0.f;
  if (isf32) {
    const float* p = (isA ? (const float*)Araw : (const float*)Braw) + r * KDIM;
#pragma unroll
    for (int it = 0; it < KDIM / 256; ++it) {
      float4 v = *((const float4*)p + it * 64 + lane);
      s = fmaf(v.x, v.x, fmaf(v.y, v.y, fmaf(v.z, v.z, fmaf(v.w, v.w, s))));
      uint2 o;
      o.x = pack_rn(__float_as_uint(v.x), __float_as_uint(v.y));
      o.y = pack_rn(__float_as_uint(v.z), __float_as_uint(v.w));
      dst[it * 64 + lane] = o;
    }
  } else {
    const uint16_t* p =
        (isA ? (const uint16_t*)Araw : (const uint16_t*)Braw) + r * KDIM;
#pragma unroll
    for (int it = 0; it < KDIM / 256; ++it) {
      uint2 v = *((const uint2*)p + it * 64 + lane);
      float e0 = __uint_as_float(v.x << 16);
      float e1 = __uint_as_float(v.x & 0xFFFF0000u);
      float e2 = __uint_as_float(v.y << 16);
      float e3 = __uint_as_float(v.y & 0xFFFF0000u);
      s = fmaf(e0, e0, fmaf(e1, e1, fmaf(e2, e2, fmaf(e3, e3, s))));
      dst[it * 64 + lane] = v;
    }
  }
#pragma unroll
  for (int o = 32; o > 0; o >>= 1) s += __shfl_down(s, o, 64);
  if (lane == 0) {
    if (isA) fsq[r] = s;
    else     psq[r] = s;
  }
}

// ----------------------------------------------------------------- GEMM ----
__global__ __launch_bounds__(256) void gemm_kernel(
    const uint16_t* __restrict__ Abf, const uint16_t* __restrict__ Bbf,
    const float* __restrict__ fsq, const float* __restrict__ psq,
    float* __restrict__ out, int M, int N) {
  // rows of 64B (16 u32 = 32 bf16); chunk c of row r holds global k-chunk
  // c ^ ((r>>1)&3)  (inverse-swizzled SOURCE, linear dest -- rule #21)
  __shared__ uint32_t Ab[2][BM][16];
  __shared__ uint32_t Bb[2][BN][16];

  const int tid = threadIdx.x;
  const int lane = tid & 63;
  const int wave = tid >> 6;

  // XCD-chunked block swizzle (nwg divisible by 8 -> bijective)
  const int gx = gridDim.x, gy = gridDim.y;
  const int nwg = gx * gy;
  int id = blockIdx.y * gx + blockIdx.x;
  if ((nwg & 7) == 0) id = (id & 7) * (nwg >> 3) + (id >> 3);
  const int m0 = (id / gx) * BM;
  const int n0 = (id % gx) * BN;

  const int wr = wave >> 1;   // wave row band (0..1) -> 64 rows
  const int wc = wave & 1;    // wave col band (0..1) -> 64 cols
  const int lr = lane & 15;   // fragment row/col within 16
  const int lg = lane >> 4;   // k-group == logical LDS chunk

  const int wbase = (tid & ~63);  // wave*64, uniform in wave

  auto stage = [&](int b, int ks) {
#pragma unroll
    for (int l = 0; l < 2; ++l) {
      const int f = l * 256 + tid;      // flat 16B-chunk id, lane-ordered
      const int row = f >> 2;
      const int gc = (f & 3) ^ ((row >> 1) & 3);  // pre-swizzled source chunk
      uint32_t* la = &Ab[b][0][0] + (l * 256 + wbase) * 4;  // wave-uniform
      uint32_t* lb = &Bb[b][0][0] + (l * 256 + wbase) * 4;
      int gm = m0 + row; gm = gm < M ? gm : M - 1;
      int gn = n0 + row; gn = gn < N ? gn : N - 1;  // clamp tail rows
      gload_lds16(Abf + (size_t)gm * KDIM + ks * BKS + gc * 8, la);
      gload_lds16(Bbf + (size_t)gn * KDIM + ks * BKS + gc * 8, lb);
    }
  };

  f32x4 acc[4][4] = {};

  stage(0, 0);
  __syncthreads();

  for (int ks = 0; ks < NSTEPS; ++ks) {
    const int buf = ks & 1;
    if (ks + 1 < NSTEPS) stage(buf ^ 1, ks + 1);  // async, drains at barrier

    bf16x8 ah[4], bh[4];
#pragma unroll
    for (int i = 0; i < 4; ++i) {
      const int r = wr * 64 + i * 16 + lr;
      const int pc = (lg ^ ((r >> 1) & 3)) * 4;   // swizzled read (0-conflict)
      ah[i] = *(const bf16x8*)&Ab[buf][r][pc];
    }
#pragma unroll
    for (int j = 0; j < 4; ++j) {
      const int r = wc * 64 + j * 16 + lr;
      const int pc = (lg ^ ((r >> 1) & 3)) * 4;
      bh[j] = *(const bf16x8*)&Bb[buf][r][pc];
    }

#pragma unroll
    for (int i = 0; i < 4; ++i)
#pragma unroll
      for (int j = 0; j < 4; ++j)
        acc[i][j] = __builtin_amdgcn_mfma_f32_16x16x32_bf16(ah[i], bh[j],
                                                            acc[i][j], 0, 0, 0);

    __syncthreads();
  }

  // ---- epilogue: C/D layout col=lane&15, row=(lane>>4)*4+reg (verified) ----
#pragma unroll
  for (int j = 0; j < 4; ++j) {
    const int n = n0 + wc * 64 + j * 16 + lr;
    if (n >= N) continue;
    const float pn = psq[n];
#pragma unroll
    for (int i = 0; i < 4; ++i) {
      const int mb = m0 + wr * 64 + i * 16 + lg * 4;
#pragma unroll
      for (int r = 0; r < 4; ++r) {
        const int m = mb + r;
        if (m < M) {
          const float d2 = fsq[m] + pn - 2.f * acc[i][j][r];
          out[(size_t)m * N + n] = -sqrtf(fmaxf(d2, 0.f));
        }
      }
    }
  }
}

// ------------------------------------ fallback (round-2 verified, fused) ----
__global__ __launch_bounds__(256) void dist_mfma_kernel(
    const void* __restrict__ Araw, const void* __restrict__ Braw,
    float* __restrict__ out, int M, int N) {
  __shared__ uint32_t Ah[2][BM][16];
  __shared__ uint32_t Bh[2][BN][16];
  __shared__ float fsqs[BM];
  __shared__ float psqs[BN];

  const bool isf32 = sniff_is_f32(Araw);
  const int tid = threadIdx.x;
  const int lane = tid & 63;
  const int wave = tid >> 6;
  const int m0 = blockIdx.y * BM;
  const int n0 = blockIdx.x * BN;

  const float* A32 = (const float*)Araw;
  const float* B32 = (const float*)Braw;
  const uint16_t* A16 = (const uint16_t*)Araw;
  const uint16_t* B16 = (const uint16_t*)Braw;

  const int crow = tid >> 2;
  const int cch = tid & 3;
  const int wr = wave >> 1;
  const int wc = wave & 1;
  const int lr = lane & 15;
  const int lg = lane >> 4;

  uint4 qa0[2], qa1[2], qb0[2], qb1[2];
  float na[2] = {0.f, 0.f};
  float nb[2] = {0.f, 0.f};

  auto load_step = [&](int ks) {
#pragma unroll
    for (int s = 0; s < 2; ++s) {
      const int row = crow + 64 * s;
      int gm = m0 + row; gm = gm < M ? gm : M - 1;
      int gn = n0 + row; gn = gn < N ? gn : N - 1;
      const size_t ea = (size_t)gm * KDIM + ks * BKS + cch * 8;
      const size_t eb = (size_t)gn * KDIM + ks * BKS + cch * 8;
      if (isf32) {
        qa0[s] = *(const uint4*)(A32 + ea);
        qa1[s] = *(const uint4*)(A32 + ea + 4);
        qb0[s] = *(const uint4*)(B32 + eb);
        qb1[s] = *(const uint4*)(B32 + eb + 4);
      } else {
        qa0[s] = *(const uint4*)(A16 + ea);
        qb0[s] = *(const uint4*)(B16 + eb);
      }
    }
  };

  auto store_step = [&](int b) {
#pragma unroll
    for (int s = 0; s < 2; ++s) {
      const int row = crow + 64 * s;
      const int pc = (cch ^ ((row >> 1) & 3)) * 4;
      if (isf32) {
        const uint32_t ua[8] = {qa0[s].x, qa0[s].y, qa0[s].z, qa0[s].w,
                                qa1[s].x, qa1[s].y, qa1[s].z, qa1[s].w};
        const uint32_t ub[8] = {qb0[s].x, qb0[s].y, qb0[s].z, qb0[s].w,
                                qb1[s].x, qb1[s].y, qb1[s].z, qb1[s].w};
        float sa = 0.f, sb = 0.f;
#pragma unroll
        for (int j = 0; j < 8; ++j) {
          const float fa = __uint_as_float(ua[j]);
          const float fb = __uint_as_float(ub[j]);
          sa = fmaf(fa, fa, sa);
          sb = fmaf(fb, fb, sb);
        }
        na[s] += sa; nb[s] += sb;
        uint4 pa = {pack_rn(ua[0], ua[1]), pack_rn(ua[2], ua[3]),
                    pack_rn(ua[4], ua[5]), pack_rn(ua[6], ua[7])};
        uint4 pb = {pack_rn(ub[0], ub[1]), pack_rn(ub[2], ub[3]),
                    pack_rn(ub[4], ub[5]), pack_rn(ub[6], ub[7])};
        *(uint4*)&Ah[b][row][pc] = pa;
        *(uint4*)&Bh[b][row][pc] = pb;
      } else {
        const uint32_t va[4] = {qa0[s].x, qa0[s].y, qa0[s].z, qa0[s].w};
        const uint32_t vb[4] = {qb0[s].x, qb0[s].y, qb0[s].z, qb0[s].w};
        float sa = 0.f, sb = 0.f;
#pragma unroll
        for (int j = 0; j < 4; ++j) {
          const float a0 = __uint_as_float(va[j] << 16);
          const float a1 = __uint_as_float(va[j] & 0xFFFF0000u);
          const float b0 = __uint_as_float(vb[j] << 16);
          const float b1 = __uint_as_float(vb[j] & 0xFFFF0000u);
          sa = fmaf(a0, a0, fmaf(a1, a1, sa));
          sb = fmaf(b0, b0, fmaf(b1, b1, sb));
        }
        na[s] += sa; nb[s] += sb;
        *(uint4*)&Ah[b][row][pc] = qa0[s];
        *(uint4*)&Bh[b][row][pc] = qb0[s];
      }
    }
  };

  f32x4 acc[4][4] = {};
  load_step(0);
  store_step(0);
  __syncthreads();

  for (int ks = 0; ks < NSTEPS; ++ks) {
    const int buf = ks & 1;
    const int nxt = ks + 1;
    if (nxt < NSTEPS) load_step(nxt);

    bf16x8 ah[4], bh[4];
#pragma unroll
    for (int i = 0; i < 4; ++i) {
      const int r = wr * 64 + i * 16 + lr;
      const int pc = (lg ^ ((r >> 1) & 3)) * 4;
      ah[i] = *(const bf16x8*)&Ah[buf][r][pc];
    }
#pragma unroll
    for (int j = 0; j < 4; ++j) {
      const int r = wc * 64 + j * 16 + lr;
      const int pc = (lg ^ ((r >> 1) & 3)) * 4;
      bh[j] = *(const bf16x8*)&Bh[buf][r][pc];
    }

#pragma unroll
    for (int i = 0; i < 4; ++i)
#pragma unroll
      for (int j = 0; j < 4; ++j)
        acc[i][j] = __builtin_amdgcn_mfma_f32_16x16x32_bf16(ah[i], bh[j],
                                                            acc[i][j], 0, 0, 0);

    if (nxt < NSTEPS) store_step(nxt & 1);
    __syncthreads();
  }

  float v0 = na[0], v1 = na[1], w0 = nb[0], w1 = nb[1];
#pragma unroll
  for (int o = 1; o <= 2; o <<= 1) {
    v0 += __shfl_xor(v0, o);
    v1 += __shfl_xor(v1, o);
    w0 += __shfl_xor(w0, o);
    w1 += __shfl_xor(w1, o);
  }
  if (cch == 0) {
    fsqs[crow] = v0;
    fsqs[crow + 64] = v1;
    psqs[crow] = w0;
    psqs[crow + 64] = w1;
  }
  __syncthreads();

#pragma unroll
  for (int j = 0; j < 4; ++j) {
    const int nn = wc * 64 + j * 16 + lr;
    const int n = n0 + nn;
    if (n >= N) continue;
    const float pn = psqs[nn];
#pragma unroll
    for (int i = 0; i < 4; ++i) {
      const int mb = wr * 64 + i * 16 + lg * 4;
#pragma unroll
      for (int r = 0; r < 4; ++r) {
        const int m = m0 + mb + r;
        if (m < M) {
          const float d2 = fsqs[mb + r] + pn - 2.f * acc[i][j][r];
          out[(size_t)m * N + n] = -sqrtf(fmaxf(d2, 0.f));
        }
      }
    }
  }
}

// -------------------------------------------------------------- launcher ----
extern "C" void kernel_launch(void* const* d_in, const int* in_sizes, int n_in,
                              void* d_out, int out_size, void* d_ws,
                              size_t ws_size, hipStream_t stream) {
  (void)n_in; (void)out_size;
  const void* feat = d_in[0];
  const void* prot = d_in[1];
  float* out = (float*)d_out;

  const int M = in_sizes[0] / KDIM;  // 16384 (element counts, dtype-free)
  const int N = in_sizes[1] / KDIM;  // 1000

  // ws layout: Abf [M*K bf16] | Bbf [N*K bf16] | fsq [M f32] | psq [N f32]
  const size_t bfA = (size_t)M * KDIM * sizeof(uint16_t);
  const size_t bfB = (size_t)N * KDIM * sizeof(uint16_t);
  const size_t ws_need = bfA + bfB + (size_t)(M + N) * sizeof(float);

  if (d_ws != nullptr && ws_size >= ws_need) {
    uint16_t* Abf = (uint16_t*)d_ws;
    uint16_t* Bbf = (uint16_t*)((char*)d_ws + bfA);
    float* fsq = (float*)((char*)d_ws + bfA + bfB);
    float* psq = fsq + M;
    const int rows = M + N;
    prep_kernel<<<dim3((rows + 3) / 4), dim3(256), 0, stream>>>(
        feat, prot, Abf, Bbf, fsq, psq, M, N);
    dim3 grid((N + BN - 1) / BN, (M + BM - 1) / BM);
    gemm_kernel<<<grid, dim3(256), 0, stream>>>(Abf, Bbf, fsq, psq, out, M, N);
  } else {
    dim3 grid((N + BN - 1) / BN, (M + BM - 1) / BM);
    dist_mfma_kernel<<<grid, dim3(256), 0, stream>>>(feat, prot, out, M, N);
  }
}

// Round 4
// 344.048 us; speedup vs baseline: 5.7769x; 1.0168x over previous
//
#include <hip/hip_runtime.h>
#include <stdint.h>

// out[m,n] = -sqrt( ||A[m]||^2 + ||B[n]||^2 - 2*A[m].B[n] )
// A = features [M=16384, K=2048], B = prototypes [N=1000, K=2048].
//
// Stage plan (ws >= 71.3 MB):
//  1. prep_kernel: fp32 -> bf16(rne) of A,B into workspace + exact fp32 row
//     norms. (bf16 input: plain copy + norms.)
//  2. gemm_kernel: bf16 MFMA GEMM, 128x128 tile, 4 waves, 16x16x32.
//     NEW this round: depth-3 pipeline -- 4-deep LDS ring, global_load_lds
//     issued 3 K-steps ahead, counted s_waitcnt vmcnt(12) (never 0 in main
//     loop) + raw s_barrier pairs (T3/T4 mechanism; regime = HBM-latency on
//     the per-step critical path since A streams once). T5 setprio around
//     the MFMA cluster. XOR chunk swizzle via inverse-swizzled global source
//     (rule #21), verified 0 bank conflicts in rounds 1-3.
//  3. ws too small -> round-2 verified fused kernel (correctness fallback).

#define KDIM 2048
#define BM 128
#define BN 128
#define BKS 32
#define NSTEPS (KDIM / BKS)

typedef __attribute__((ext_vector_type(8))) __bf16 bf16x8;
typedef __attribute__((ext_vector_type(4))) float f32x4;

__device__ __forceinline__ bool sniff_is_f32(const void* Araw) {
  // bf16 N(0,1) data -> max |x| < 10; fp32 data -> mantissa half-words give
  // |x| > 1e4 essentially surely. Uniform across all blocks/lanes.
  const uint16_t* sniff = (const uint16_t*)Araw;
  float mx = 0.f;
#pragma unroll
  for (int i = 0; i < 64; ++i) {
    float v = __uint_as_float(((uint32_t)sniff[i]) << 16);
    mx = fmaxf(mx, fabsf(v));
  }
  return mx > 1e4f;
}

__device__ __forceinline__ uint32_t bf16rn(uint32_t u) {
  // fp32 bits -> bf16 bits, round-to-nearest-even (finite inputs only)
  return (u + 0x7FFFu + ((u >> 16) & 1u)) >> 16;
}
__device__ __forceinline__ uint32_t pack_rn(uint32_t a, uint32_t b) {
  return bf16rn(a) | (bf16rn(b) << 16);
}

__device__ __forceinline__ void gload_lds16(const void* g, void* l) {
  // async 16B global -> LDS; dest = wave-uniform base + lane*16
  __builtin_amdgcn_global_load_lds(
      (const __attribute__((address_space(1))) void*)g,
      (__attribute__((address_space(3))) void*)l, 16, 0, 0);
}

// ----------------------------------------------------- prepass: cvt+norms ----
// one wave per row; 4 rows per 256-thread block
__global__ __launch_bounds__(256) void prep_kernel(
    const void* __restrict__ Araw, const void* __restrict__ Braw,
    uint16_t* __restrict__ Abf, uint16_t* __restrict__ Bbf,
    float* __restrict__ fsq, float* __restrict__ psq, int M, int N) {
  const bool isf32 = sniff_is_f32(Araw);
  const int wave = threadIdx.x >> 6;
  const int lane = threadIdx.x & 63;
  const int row = blockIdx.x * 4 + wave;
  if (row >= M + N) return;
  const bool isA = row < M;
  const size_t r = isA ? (size_t)row : (size_t)(row - M);
  uint2* dst = (uint2*)((isA ? Abf : Bbf) + r * KDIM);
  float s = 0.f;
  if (isf32) {
    const float* p = (isA ? (const float*)Araw : (const float*)Braw) + r * KDIM;
#pragma unroll
    for (int it = 0; it < KDIM / 256; ++it) {
      float4 v = *((const float4*)p + it * 64 + lane);
      s = fmaf(v.x, v.x, fmaf(v.y, v.y, fmaf(v.z, v.z, fmaf(v.w, v.w, s))));
      uint2 o;
      o.x = pack_rn(__float_as_uint(v.x), __float_as_uint(v.y));
      o.y = pack_rn(__float_as_uint(v.z), __float_as_uint(v.w));
      dst[it * 64 + lane] = o;
    }
  } else {
    const uint16_t* p =
        (isA ? (const uint16_t*)Araw : (const uint16_t*)Braw) + r * KDIM;
#pragma unroll
    for (int it = 0; it < KDIM / 256; ++it) {
      uint2 v = *((const uint2*)p + it * 64 + lane);
      float e0 = __uint_as_float(v.x << 16);
      float e1 = __uint_as_float(v.x & 0xFFFF0000u);
      float e2 = __uint_as_float(v.y << 16);
      float e3 = __uint_as_float(v.y & 0xFFFF0000u);
      s = fmaf(e0, e0, fmaf(e1, e1, fmaf(e2, e2, fmaf(e3, e3, s))));
      dst[it * 64 + lane] = v;
    }
  }
#pragma unroll
  for (int o = 32; o > 0; o >>= 1) s += __shfl_down(s, o, 64);
  if (lane == 0) {
    if (isA) fsq[r] = s;
    else     psq[r] = s;
  }
}

// ----------------------------------------------------------------- GEMM ----
__global__ __launch_bounds__(256) void gemm_kernel(
    const uint16_t* __restrict__ Abf, const uint16_t* __restrict__ Bbf,
    const float* __restrict__ fsq, const float* __restrict__ psq,
    float* __restrict__ out, int M, int N) {
  // 4-deep ring; rows of 64B (16 u32 = 32 bf16); chunk c of row r holds
  // global k-chunk c ^ ((r>>1)&3) (inverse-swizzled SOURCE, linear dest)
  __shared__ uint32_t Ab[4][BM][16];
  __shared__ uint32_t Bb[4][BN][16];

  const int tid = threadIdx.x;
  const int lane = tid & 63;
  const int wave = tid >> 6;

  // XCD-chunked block swizzle (nwg divisible by 8 -> bijective)
  const int gx = gridDim.x, gy = gridDim.y;
  const int nwg = gx * gy;
  int id = blockIdx.y * gx + blockIdx.x;
  if ((nwg & 7) == 0) id = (id & 7) * (nwg >> 3) + (id >> 3);
  const int m0 = (id / gx) * BM;
  const int n0 = (id % gx) * BN;

  const int wr = wave >> 1;   // wave row band (0..1) -> 64 rows
  const int wc = wave & 1;    // wave col band (0..1) -> 64 cols
  const int lr = lane & 15;   // fragment row/col within 16
  const int lg = lane >> 4;   // k-group == logical LDS chunk

  const int wbase = (tid & ~63);  // wave*64, uniform in wave

  auto stage = [&](int b, int ks) {
#pragma unroll
    for (int l = 0; l < 2; ++l) {
      const int f = l * 256 + tid;      // flat 16B-chunk id, lane-ordered
      const int row = f >> 2;
      const int gc = (f & 3) ^ ((row >> 1) & 3);  // pre-swizzled source chunk
      uint32_t* la = &Ab[b][0][0] + (l * 256 + wbase) * 4;  // wave-uniform
      uint32_t* lb = &Bb[b][0][0] + (l * 256 + wbase) * 4;
      int gm = m0 + row; gm = gm < M ? gm : M - 1;
      int gn = n0 + row; gn = gn < N ? gn : N - 1;  // clamp tail rows
      gload_lds16(Abf + (size_t)gm * KDIM + ks * BKS + gc * 8, la);
      gload_lds16(Bbf + (size_t)gn * KDIM + ks * BKS + gc * 8, lb);
    }
  };

  f32x4 acc[4][4] = {};

  // prologue: fill ring slots 0..2 (4 vmem instrs per stage per thread)
  stage(0, 0);
  stage(1, 1);
  stage(2, 2);

  for (int ks = 0; ks < NSTEPS; ++ks) {
    const int buf = ks & 3;
    // issue prefetch for ks+3, then wait so that stage(ks) has landed.
    // FIFO vmcnt: after issue, outstanding <= 16; wait to 12 retires the 4
    // oldest (= stage ks). Drain tail: 8 / 4 / 0.
    if (ks + 3 < NSTEPS) {
      stage((ks + 3) & 3, ks + 3);
      asm volatile("s_waitcnt vmcnt(12)");
    } else if (ks + 2 < NSTEPS) {
      asm volatile("s_waitcnt vmcnt(8)");
    } else if (ks + 1 < NSTEPS) {
      asm volatile("s_waitcnt vmcnt(4)");
    } else {
      asm volatile("s_waitcnt vmcnt(0)");
    }
    __builtin_amdgcn_s_barrier();      // everyone's stage(ks) visible
    asm volatile("" ::: "memory");     // no LDS-read hoisting above barrier

    bf16x8 ah[4], bh[4];
#pragma unroll
    for (int i = 0; i < 4; ++i) {
      const int r = wr * 64 + i * 16 + lr;
      const int pc = (lg ^ ((r >> 1) & 3)) * 4;   // swizzled read (0-conflict)
      ah[i] = *(const bf16x8*)&Ab[buf][r][pc];
    }
#pragma unroll
    for (int j = 0; j < 4; ++j) {
      const int r = wc * 64 + j * 16 + lr;
      const int pc = (lg ^ ((r >> 1) & 3)) * 4;
      bh[j] = *(const bf16x8*)&Bb[buf][r][pc];
    }

    __builtin_amdgcn_s_setprio(1);
#pragma unroll
    for (int i = 0; i < 4; ++i)
#pragma unroll
      for (int j = 0; j < 4; ++j)
        acc[i][j] = __builtin_amdgcn_mfma_f32_16x16x32_bf16(ah[i], bh[j],
                                                            acc[i][j], 0, 0, 0);
    __builtin_amdgcn_s_setprio(0);

    // write-after-read guard: next iter's stage targets buf (ks+4)&3 == buf;
    // this barrier proves every wave's ds_reads of buf completed (their
    // MFMAs consumed them under compiler lgkm waits before arriving here).
    __builtin_amdgcn_s_barrier();
    asm volatile("" ::: "memory");
  }

  // ---- epilogue: C/D layout col=lane&15, row=(lane>>4)*4+reg (verified) ----
#pragma unroll
  for (int j = 0; j < 4; ++j) {
    const int n = n0 + wc * 64 + j * 16 + lr;
    if (n >= N) continue;
    const float pn = psq[n];
#pragma unroll
    for (int i = 0; i < 4; ++i) {
      const int mb = m0 + wr * 64 + i * 16 + lg * 4;
#pragma unroll
      for (int r = 0; r < 4; ++r) {
        const int m = mb + r;
        if (m < M) {
          const float d2 = fsq[m] + pn - 2.f * acc[i][j][r];
          out[(size_t)m * N + n] = -sqrtf(fmaxf(d2, 0.f));
        }
      }
    }
  }
}

// ------------------------------------ fallback (round-2 verified, fused) ----
__global__ __launch_bounds__(256) void dist_mfma_kernel(
    const void* __restrict__ Araw, const void* __restrict__ Braw,
    float* __restrict__ out, int M, int N) {
  __shared__ uint32_t Ah[2][BM][16];
  __shared__ uint32_t Bh[2][BN][16];
  __shared__ float fsqs[BM];
  __shared__ float psqs[BN];

  const bool isf32 = sniff_is_f32(Araw);
  const int tid = threadIdx.x;
  const int lane = tid & 63;
  const int wave = tid >> 6;
  const int m0 = blockIdx.y * BM;
  const int n0 = blockIdx.x * BN;

  const float* A32 = (const float*)Araw;
  const float* B32 = (const float*)Braw;
  const uint16_t* A16 = (const uint16_t*)Araw;
  const uint16_t* B16 = (const uint16_t*)Braw;

  const int crow = tid >> 2;
  const int cch = tid & 3;
  const int wr = wave >> 1;
  const int wc = wave & 1;
  const int lr = lane & 15;
  const int lg = lane >> 4;

  uint4 qa0[2], qa1[2], qb0[2], qb1[2];
  float na[2] = {0.f, 0.f};
  float nb[2] = {0.f, 0.f};

  auto load_step = [&](int ks) {
#pragma unroll
    for (int s = 0; s < 2; ++s) {
      const int row = crow + 64 * s;
      int gm = m0 + row; gm = gm < M ? gm : M - 1;
      int gn = n0 + row; gn = gn < N ? gn : N - 1;
      const size_t ea = (size_t)gm * KDIM + ks * BKS + cch * 8;
      const size_t eb = (size_t)gn * KDIM + ks * BKS + cch * 8;
      if (isf32) {
        qa0[s] = *(const uint4*)(A32 + ea);
        qa1[s] = *(const uint4*)(A32 + ea + 4);
        qb0[s] = *(const uint4*)(B32 + eb);
        qb1[s] = *(const uint4*)(B32 + eb + 4);
      } else {
        qa0[s] = *(const uint4*)(A16 + ea);
        qb0[s] = *(const uint4*)(B16 + eb);
      }
    }
  };

  auto store_step = [&](int b) {
#pragma unroll
    for (int s = 0; s < 2; ++s) {
      const int row = crow + 64 * s;
      const int pc = (cch ^ ((row >> 1) & 3)) * 4;
      if (isf32) {
        const uint32_t ua[8] = {qa0[s].x, qa0[s].y, qa0[s].z, qa0[s].w,
                                qa1[s].x, qa1[s].y, qa1[s].z, qa1[s].w};
        const uint32_t ub[8] = {qb0[s].x, qb0[s].y, qb0[s].z, qb0[s].w,
                                qb1[s].x, qb1[s].y, qb1[s].z, qb1[s].w};
        float sa = 0.f, sb = 0.f;
#pragma unroll
        for (int j = 0; j < 8; ++j) {
          const float fa = __uint_as_float(ua[j]);
          const float fb = __uint_as_float(ub[j]);
          sa = fmaf(fa, fa, sa);
          sb = fmaf(fb, fb, sb);
        }
        na[s] += sa; nb[s] += sb;
        uint4 pa = {pack_rn(ua[0], ua[1]), pack_rn(ua[2], ua[3]),
                    pack_rn(ua[4], ua[5]), pack_rn(ua[6], ua[7])};
        uint4 pb = {pack_rn(ub[0], ub[1]), pack_rn(ub[2], ub[3]),
                    pack_rn(ub[4], ub[5]), pack_rn(ub[6], ub[7])};
        *(uint4*)&Ah[b][row][pc] = pa;
        *(uint4*)&Bh[b][row][pc] = pb;
      } else {
        const uint32_t va[4] = {qa0[s].x, qa0[s].y, qa0[s].z, qa0[s].w};
        const uint32_t vb[4] = {qb0[s].x, qb0[s].y, qb0[s].z, qb0[s].w};
        float sa = 0.f, sb = 0.f;
#pragma unroll
        for (int j = 0; j < 4; ++j) {
          const float a0 = __uint_as_float(va[j] << 16);
          const float a1 = __uint_as_float(va[j] & 0xFFFF0000u);
          const float b0 = __uint_as_float(vb[j] << 16);
          const float b1 = __uint_as_float(vb[j] & 0xFFFF0000u);
          sa = fmaf(a0, a0, fmaf(a1, a1, sa));
          sb = fmaf(b0, b0, fmaf(b1, b1, sb));
        }
        na[s] += sa; nb[s] += sb;
        *(uint4*)&Ah[b][row][pc] = qa0[s];
        *(uint4*)&Bh[b][row][pc] = qb0[s];
      }
    }
  };

  f32x4 acc[4][4] = {};
  load_step(0);
  store_step(0);
  __syncthreads();

  for (int ks = 0; ks < NSTEPS; ++ks) {
    const int buf = ks & 1;
    const int nxt = ks + 1;
    if (nxt < NSTEPS) load_step(nxt);

    bf16x8 ah[4], bh[4];
#pragma unroll
    for (int i = 0; i < 4; ++i) {
      const int r = wr * 64 + i * 16 + lr;
      const int pc = (lg ^ ((r >> 1) & 3)) * 4;
      ah[i] = *(const bf16x8*)&Ah[buf][r][pc];
    }
#pragma unroll
    for (int j = 0; j < 4; ++j) {
      const int r = wc * 64 + j * 16 + lr;
      const int pc = (lg ^ ((r >> 1) & 3)) * 4;
      bh[j] = *(const bf16x8*)&Bh[buf][r][pc];
    }

#pragma unroll
    for (int i = 0; i < 4; ++i)
#pragma unroll
      for (int j = 0; j < 4; ++j)
        acc[i][j] = __builtin_amdgcn_mfma_f32_16x16x32_bf16(ah[i], bh[j],
                                                            acc[i][j], 0, 0, 0);

    if (nxt < NSTEPS) store_step(nxt & 1);
    __syncthreads();
  }

  float v0 = na[0], v1 = na[1], w0 = nb[0], w1 = nb[1];
#pragma unroll
  for (int o = 1; o <= 2; o <<= 1) {
    v0 += __shfl_xor(v0, o);
    v1 += __shfl_xor(v1, o);
    w0 += __shfl_xor(w0, o);
    w1 += __shfl_xor(w1, o);
  }
  if (cch == 0) {
    fsqs[crow] = v0;
    fsqs[crow + 64] = v1;
    psqs[crow] = w0;
    psqs[crow + 64] = w1;
  }
  __syncthreads();

#pragma unroll
  for (int j = 0; j < 4; ++j) {
    const int nn = wc * 64 + j * 16 + lr;
    const int n = n0 + nn;
    if (n >= N) continue;
    const float pn = psqs[nn];
#pragma unroll
    for (int i = 0; i < 4; ++i) {
      const int mb = wr * 64 + i * 16 + lg * 4;
#pragma unroll
      for (int r = 0; r < 4; ++r) {
        const int m = m0 + mb + r;
        if (m < M) {
          const float d2 = fsqs[mb + r] + pn - 2.f * acc[i][j][r];
          out[(size_t)m * N + n] = -sqrtf(fmaxf(d2, 0.f));
        }
      }
    }
  }
}

// -------------------------------------------------------------- launcher ----
extern "C" void kernel_launch(void* const* d_in, const int* in_sizes, int n_in,
                              void* d_out, int out_size, void* d_ws,
                              size_t ws_size, hipStream_t stream) {
  (void)n_in; (void)out_size;
  const void* feat = d_in[0];
  const void* prot = d_in[1];
  float* out = (float*)d_out;

  const int M = in_sizes[0] / KDIM;  // 16384 (element counts, dtype-free)
  const int N = in_sizes[1] / KDIM;  // 1000

  // ws layout: Abf [M*K bf16] | Bbf [N*K bf16] | fsq [M f32] | psq [N f32]
  const size_t bfA = (size_t)M * KDIM * sizeof(uint16_t);
  const size_t bfB = (size_t)N * KDIM * sizeof(uint16_t);
  const size_t ws_need = bfA + bfB + (size_t)(M + N) * sizeof(float);

  if (d_ws != nullptr && ws_size >= ws_need) {
    uint16_t* Abf = (uint16_t*)d_ws;
    uint16_t* Bbf = (uint16_t*)((char*)d_ws + bfA);
    float* fsq = (float*)((char*)d_ws + bfA + bfB);
    float* psq = fsq + M;
    const int rows = M + N;
    prep_kernel<<<dim3((rows + 3) / 4), dim3(256), 0, stream>>>(
        feat, prot, Abf, Bbf, fsq, psq, M, N);
    dim3 grid((N + BN - 1) / BN, (M + BM - 1) / BM);
    gemm_kernel<<<grid, dim3(256), 0, stream>>>(Abf, Bbf, fsq, psq, out, M, N);
  } else {
    dim3 grid((N + BN - 1) / BN, (M + BM - 1) / BM);
    dist_mfma_kernel<<<grid, dim3(256), 0, stream>>>(feat, prot, out, M, N);
  }
}

// Round 5
// 322.014 us; speedup vs baseline: 6.1722x; 1.0684x over previous
//
#include <hip/hip_runtime.h>
#include <stdint.h>

// out[m,n] = -sqrt( ||A[m]||^2 + ||B[n]||^2 - 2*A[m].B[n] )
// A = features [M=16384, K=2048], B = prototypes [N=1000, K=2048].
//
// Stage plan (ws >= 71.3 MB):
//  1. prep_kernel: fp32 -> bf16(rne) of A,B into workspace + exact fp32 row
//     norms. (bf16 input: plain copy + norms.)
//  2. gemm_kernel: 256x256 tile, BK=64, 512 threads (8 waves, 2Mx4N), 128 KiB
//     double-buffered LDS, 16x16x32 bf16 MFMA, 64 MFMA/wave/K-step.
//     Rounds-3/4-verified sync idiom: stage-issue -> counted vmcnt(8) ->
//     s_barrier -> compute -> s_barrier. Linear LDS dest + inverse-swizzled
//     global source (chunk ^= row&7), swizzled ds_read (0 conflicts expected).
//     Grid 256 blocks = 1/CU; XCD-chunked swizzle groups each A-panel's 4
//     column-blocks on one XCD. T5 setprio around MFMA cluster.
//  3. ws too small -> round-2 verified fused kernel (correctness fallback).

#define KDIM 2048

typedef __attribute__((ext_vector_type(8))) __bf16 bf16x8;
typedef __attribute__((ext_vector_type(4))) float f32x4;

__device__ __forceinline__ bool sniff_is_f32(const void* Araw) {
  // bf16 N(0,1) data -> max |x| < 10; fp32 data -> mantissa half-words give
  // |x| > 1e4 essentially surely. Uniform across all blocks/lanes.
  const uint16_t* sniff = (const uint16_t*)Araw;
  float mx = 0.f;
#pragma unroll
  for (int i = 0; i < 64; ++i) {
    float v = __uint_as_float(((uint32_t)sniff[i]) << 16);
    mx = fmaxf(mx, fabsf(v));
  }
  return mx > 1e4f;
}

__device__ __forceinline__ uint32_t bf16rn(uint32_t u) {
  // fp32 bits -> bf16 bits, round-to-nearest-even (finite inputs only)
  return (u + 0x7FFFu + ((u >> 16) & 1u)) >> 16;
}
__device__ __forceinline__ uint32_t pack_rn(uint32_t a, uint32_t b) {
  return bf16rn(a) | (bf16rn(b) << 16);
}

__device__ __forceinline__ void gload_lds16(const void* g, void* l) {
  // async 16B global -> LDS; dest = wave-uniform base + lane*16
  __builtin_amdgcn_global_load_lds(
      (const __attribute__((address_space(1))) void*)g,
      (__attribute__((address_space(3))) void*)l, 16, 0, 0);
}

// ----------------------------------------------------- prepass: cvt+norms ----
// one wave per row; 4 rows per 256-thread block
__global__ __launch_bounds__(256) void prep_kernel(
    const void* __restrict__ Araw, const void* __restrict__ Braw,
    uint16_t* __restrict__ Abf, uint16_t* __restrict__ Bbf,
    float* __restrict__ fsq, float* __restrict__ psq, int M, int N) {
  const bool isf32 = sniff_is_f32(Araw);
  const int wave = threadIdx.x >> 6;
  const int lane = threadIdx.x & 63;
  const int row = blockIdx.x * 4 + wave;
  if (row >= M + N) return;
  const bool isA = row < M;
  const size_t r = isA ? (size_t)row : (size_t)(row - M);
  uint2* dst = (uint2*)((isA ? Abf : Bbf) + r * KDIM);
  float s = 0.f;
  if (isf32) {
    const float* p = (isA ? (const float*)Araw : (const float*)Braw) + r * KDIM;
#pragma unroll
    for (int it = 0; it < KDIM / 256; ++it) {
      float4 v = *((const float4*)p + it * 64 + lane);
      s = fmaf(v.x, v.x, fmaf(v.y, v.y, fmaf(v.z, v.z, fmaf(v.w, v.w, s))));
      uint2 o;
      o.x = pack_rn(__float_as_uint(v.x), __float_as_uint(v.y));
      o.y = pack_rn(__float_as_uint(v.z), __float_as_uint(v.w));
      dst[it * 64 + lane] = o;
    }
  } else {
    const uint16_t* p =
        (isA ? (const uint16_t*)Araw : (const uint16_t*)Braw) + r * KDIM;
#pragma unroll
    for (int it = 0; it < KDIM / 256; ++it) {
      uint2 v = *((const uint2*)p + it * 64 + lane);
      float e0 = __uint_as_float(v.x << 16);
      float e1 = __uint_as_float(v.x & 0xFFFF0000u);
      float e2 = __uint_as_float(v.y << 16);
      float e3 = __uint_as_float(v.y & 0xFFFF0000u);
      s = fmaf(e0, e0, fmaf(e1, e1, fmaf(e2, e2, fmaf(e3, e3, s))));
      dst[it * 64 + lane] = v;
    }
  }
#pragma unroll
  for (int o = 32; o > 0; o >>= 1) s += __shfl_down(s, o, 64);
  if (lane == 0) {
    if (isA) fsq[r] = s;
    else     psq[r] = s;
  }
}

// --------------------------------------------------- GEMM 256x256, BK=64 ----
#define BM2 256
#define BN2 256
#define BK2 64
#define NK2 (KDIM / BK2)   // 32

__global__ __launch_bounds__(512, 2) void gemm_kernel(
    const uint16_t* __restrict__ Abf, const uint16_t* __restrict__ Bbf,
    const float* __restrict__ fsq, const float* __restrict__ psq,
    float* __restrict__ out, int M, int N) {
  // row = 64 bf16 = 128 B = 8 chunks of 16 B. LDS chunk c of row r holds
  // global k-chunk c ^ (r&7)  (inverse-swizzled SOURCE, linear dest).
  __shared__ uint32_t Ab[2][BM2][32];  // 64 KB
  __shared__ uint32_t Bb[2][BN2][32];  // 64 KB

  const int tid = threadIdx.x;
  const int lane = tid & 63;
  const int wave = tid >> 6;   // 0..7

  // XCD-chunked block swizzle (nwg = 256, divisible by 8 -> bijective).
  // XCD x gets 32 consecutive tile-ids = 8 complete A-panels (gx=4).
  const int gx = gridDim.x, gy = gridDim.y;
  const int nwg = gx * gy;
  int id = blockIdx.y * gx + blockIdx.x;
  if ((nwg & 7) == 0) id = (id & 7) * (nwg >> 3) + (id >> 3);
  const int m0 = (id / gx) * BM2;
  const int n0 = (id % gx) * BN2;

  const int wr = wave >> 2;   // 0..1: 128-row band
  const int wc = wave & 3;    // 0..3: 64-col band
  const int lr = lane & 15;   // fragment row/col within 16
  const int lg = lane >> 4;   // k-group within 4

  const int wbase = (tid & ~63);  // wave*64, uniform in wave

  auto stage = [&](int b, int ks) {
#pragma unroll
    for (int p = 0; p < 4; ++p) {
      const int f = p * 512 + tid;     // flat 16B-chunk id, lane-ordered
      const int row = f >> 3;          // 0..255
      const int gc = (f & 7) ^ (row & 7);  // pre-swizzled source chunk
      uint32_t* la = &Ab[b][0][0] + (p * 512 + wbase) * 4;  // wave-uniform
      uint32_t* lb = &Bb[b][0][0] + (p * 512 + wbase) * 4;
      int gm = m0 + row; gm = gm < M ? gm : M - 1;
      int gn = n0 + row; gn = gn < N ? gn : N - 1;  // clamp tail rows
      gload_lds16(Abf + (size_t)gm * KDIM + ks * BK2 + gc * 8, la);
      gload_lds16(Bbf + (size_t)gn * KDIM + ks * BK2 + gc * 8, lb);
    }
  };

  f32x4 acc[8][4] = {};

  stage(0, 0);

  for (int ks = 0; ks < NK2; ++ks) {
    const int buf = ks & 1;
    // Prefetch next K-tile into the other buffer. WAR-safe: that buffer's
    // ds_reads completed before the previous step's trailing barrier.
    // FIFO vmcnt: after issue, 16 outstanding; wait to 8 retires the oldest
    // 8 = stage(ks). One K-step (~1 us) in flight >> HBM latency.
    if (ks + 1 < NK2) {
      stage(buf ^ 1, ks + 1);
      asm volatile("s_waitcnt vmcnt(8)");
    } else {
      asm volatile("s_waitcnt vmcnt(0)");
    }
    __builtin_amdgcn_s_barrier();      // everyone's stage(ks) visible
    asm volatile("" ::: "memory");     // no LDS-read hoisting above barrier

    // B fragments for this wave's 64-col band (8 ds_read_b128)
    bf16x8 bh[4][2];
#pragma unroll
    for (int nj = 0; nj < 4; ++nj) {
      const int r = wc * 64 + nj * 16 + lr;
#pragma unroll
      for (int kk = 0; kk < 2; ++kk) {
        const int pc = ((kk * 4 + lg) ^ (r & 7)) * 4;
        bh[nj][kk] = *(const bf16x8*)&Bb[buf][r][pc];
      }
    }

    __builtin_amdgcn_s_setprio(1);
#pragma unroll
    for (int mi = 0; mi < 8; ++mi) {
      const int r = wr * 128 + mi * 16 + lr;
      const int p0 = ((0 + lg) ^ (r & 7)) * 4;
      const int p1 = ((4 + lg) ^ (r & 7)) * 4;
      const bf16x8 a0 = *(const bf16x8*)&Ab[buf][r][p0];
      const bf16x8 a1 = *(const bf16x8*)&Ab[buf][r][p1];
#pragma unroll
      for (int nj = 0; nj < 4; ++nj) {
        acc[mi][nj] = __builtin_amdgcn_mfma_f32_16x16x32_bf16(
            a0, bh[nj][0], acc[mi][nj], 0, 0, 0);
        acc[mi][nj] = __builtin_amdgcn_mfma_f32_16x16x32_bf16(
            a1, bh[nj][1], acc[mi][nj], 0, 0, 0);
      }
    }
    __builtin_amdgcn_s_setprio(0);

    // WAR guard: next step's stage overwrites buf^1 only after this barrier
    // proves every wave's ds_reads of buf^1... (consumed last step) and the
    // current buf's reads are long done (lgkm-waited before their MFMAs).
    __builtin_amdgcn_s_barrier();
    asm volatile("" ::: "memory");
  }

  // ---- epilogue: C/D layout col=lane&15, row=(lane>>4)*4+reg (verified) ----
#pragma unroll
  for (int nj = 0; nj < 4; ++nj) {
    const int n = n0 + wc * 64 + nj * 16 + lr;
    if (n >= N) continue;
    const float pn = psq[n];
#pragma unroll
    for (int mi = 0; mi < 8; ++mi) {
      const int mb = m0 + wr * 128 + mi * 16 + lg * 4;
#pragma unroll
      for (int r = 0; r < 4; ++r) {
        const int m = mb + r;
        if (m < M) {
          const float d2 = fsq[m] + pn - 2.f * acc[mi][nj][r];
          out[(size_t)m * N + n] = -sqrtf(fmaxf(d2, 0.f));
        }
      }
    }
  }
}

// ------------------------------------ fallback (round-2 verified, fused) ----
#define BM 128
#define BN 128
#define BKS 32
#define NSTEPS (KDIM / BKS)

__global__ __launch_bounds__(256) void dist_mfma_kernel(
    const void* __restrict__ Araw, const void* __restrict__ Braw,
    float* __restrict__ out, int M, int N) {
  __shared__ uint32_t Ah[2][BM][16];
  __shared__ uint32_t Bh[2][BN][16];
  __shared__ float fsqs[BM];
  __shared__ float psqs[BN];

  const bool isf32 = sniff_is_f32(Araw);
  const int tid = threadIdx.x;
  const int lane = tid & 63;
  const int wave = tid >> 6;
  const int m0 = blockIdx.y * BM;
  const int n0 = blockIdx.x * BN;

  const float* A32 = (const float*)Araw;
  const float* B32 = (const float*)Braw;
  const uint16_t* A16 = (const uint16_t*)Araw;
  const uint16_t* B16 = (const uint16_t*)Braw;

  const int crow = tid >> 2;
  const int cch = tid & 3;
  const int wr = wave >> 1;
  const int wc = wave & 1;
  const int lr = lane & 15;
  const int lg = lane >> 4;

  uint4 qa0[2], qa1[2], qb0[2], qb1[2];
  float na[2] = {0.f, 0.f};
  float nb[2] = {0.f, 0.f};

  auto load_step = [&](int ks) {
#pragma unroll
    for (int s = 0; s < 2; ++s) {
      const int row = crow + 64 * s;
      int gm = m0 + row; gm = gm < M ? gm : M - 1;
      int gn = n0 + row; gn = gn < N ? gn : N - 1;
      const size_t ea = (size_t)gm * KDIM + ks * BKS + cch * 8;
      const size_t eb = (size_t)gn * KDIM + ks * BKS + cch * 8;
      if (isf32) {
        qa0[s] = *(const uint4*)(A32 + ea);
        qa1[s] = *(const uint4*)(A32 + ea + 4);
        qb0[s] = *(const uint4*)(B32 + eb);
        qb1[s] = *(const uint4*)(B32 + eb + 4);
      } else {
        qa0[s] = *(const uint4*)(A16 + ea);
        qb0[s] = *(const uint4*)(B16 + eb);
      }
    }
  };

  auto store_step = [&](int b) {
#pragma unroll
    for (int s = 0; s < 2; ++s) {
      const int row = crow + 64 * s;
      const int pc = (cch ^ ((row >> 1) & 3)) * 4;
      if (isf32) {
        const uint32_t ua[8] = {qa0[s].x, qa0[s].y, qa0[s].z, qa0[s].w,
                                qa1[s].x, qa1[s].y, qa1[s].z, qa1[s].w};
        const uint32_t ub[8] = {qb0[s].x, qb0[s].y, qb0[s].z, qb0[s].w,
                                qb1[s].x, qb1[s].y, qb1[s].z, qb1[s].w};
        float sa = 0.f, sb = 0.f;
#pragma unroll
        for (int j = 0; j < 8; ++j) {
          const float fa = __uint_as_float(ua[j]);
          const float fb = __uint_as_float(ub[j]);
          sa = fmaf(fa, fa, sa);
          sb = fmaf(fb, fb, sb);
        }
        na[s] += sa; nb[s] += sb;
        uint4 pa = {pack_rn(ua[0], ua[1]), pack_rn(ua[2], ua[3]),
                    pack_rn(ua[4], ua[5]), pack_rn(ua[6], ua[7])};
        uint4 pb = {pack_rn(ub[0], ub[1]), pack_rn(ub[2], ub[3]),
                    pack_rn(ub[4], ub[5]), pack_rn(ub[6], ub[7])};
        *(uint4*)&Ah[b][row][pc] = pa;
        *(uint4*)&Bh[b][row][pc] = pb;
      } else {
        float sa = 0.f, sb = 0.f;
        const uint32_t va[4] = {qa0[s].x, qa0[s].y, qa0[s].z, qa0[s].w};
        const uint32_t vb[4] = {qb0[s].x, qb0[s].y, qb0[s].z, qb0[s].w};
#pragma unroll
        for (int j = 0; j < 4; ++j) {
          const float a0 = __uint_as_float(va[j] << 16);
          const float a1 = __uint_as_float(va[j] & 0xFFFF0000u);
          const float b0 = __uint_as_float(vb[j] << 16);
          const float b1 = __uint_as_float(vb[j] & 0xFFFF0000u);
          sa = fmaf(a0, a0, fmaf(a1, a1, sa));
          sb = fmaf(b0, b0, fmaf(b1, b1, sb));
        }
        na[s] += sa; nb[s] += sb;
        *(uint4*)&Ah[b][row][pc] = qa0[s];
        *(uint4*)&Bh[b][row][pc] = qb0[s];
      }
    }
  };

  f32x4 acc[4][4] = {};
  load_step(0);
  store_step(0);
  __syncthreads();

  for (int ks = 0; ks < NSTEPS; ++ks) {
    const int buf = ks & 1;
    const int nxt = ks + 1;
    if (nxt < NSTEPS) load_step(nxt);

    bf16x8 ah[4], bh[4];
#pragma unroll
    for (int i = 0; i < 4; ++i) {
      const int r = wr * 64 + i * 16 + lr;
      const int pc = (lg ^ ((r >> 1) & 3)) * 4;
      ah[i] = *(const bf16x8*)&Ah[buf][r][pc];
    }
#pragma unroll
    for (int j = 0; j < 4; ++j) {
      const int r = wc * 64 + j * 16 + lr;
      const int pc = (lg ^ ((r >> 1) & 3)) * 4;
      bh[j] = *(const bf16x8*)&Bh[buf][r][pc];
    }

#pragma unroll
    for (int i = 0; i < 4; ++i)
#pragma unroll
      for (int j = 0; j < 4; ++j)
        acc[i][j] = __builtin_amdgcn_mfma_f32_16x16x32_bf16(ah[i], bh[j],
                                                            acc[i][j], 0, 0, 0);

    if (nxt < NSTEPS) store_step(nxt & 1);
    __syncthreads();
  }

  float v0 = na[0], v1 = na[1], w0 = nb[0], w1 = nb[1];
#pragma unroll
  for (int o = 1; o <= 2; o <<= 1) {
    v0 += __shfl_xor(v0, o);
    v1 += __shfl_xor(v1, o);
    w0 += __shfl_xor(w0, o);
    w1 += __shfl_xor(w1, o);
  }
  if (cch == 0) {
    fsqs[crow] = v0;
    fsqs[crow + 64] = v1;
    psqs[crow] = w0;
    psqs[crow + 64] = w1;
  }
  __syncthreads();

#pragma unroll
  for (int j = 0; j < 4; ++j) {
    const int nn = wc * 64 + j * 16 + lr;
    const int n = n0 + nn;
    if (n >= N) continue;
    const float pn = psqs[nn];
#pragma unroll
    for (int i = 0; i < 4; ++i) {
      const int mb = wr * 64 + i * 16 + lg * 4;
#pragma unroll
      for (int r = 0; r < 4; ++r) {
        const int m = m0 + mb + r;
        if (m < M) {
          const float d2 = fsqs[mb + r] + pn - 2.f * acc[i][j][r];
          out[(size_t)m * N + n] = -sqrtf(fmaxf(d2, 0.f));
        }
      }
    }
  }
}

// -------------------------------------------------------------- launcher ----
extern "C" void kernel_launch(void* const* d_in, const int* in_sizes, int n_in,
                              void* d_out, int out_size, void* d_ws,
                              size_t ws_size, hipStream_t stream) {
  (void)n_in; (void)out_size;
  const void* feat = d_in[0];
  const void* prot = d_in[1];
  float* out = (float*)d_out;

  const int M = in_sizes[0] / KDIM;  // 16384 (element counts, dtype-free)
  const int N = in_sizes[1] / KDIM;  // 1000

  // ws layout: Abf [M*K bf16] | Bbf [N*K bf16] | fsq [M f32] | psq [N f32]
  const size_t bfA = (size_t)M * KDIM * sizeof(uint16_t);
  const size_t bfB = (size_t)N * KDIM * sizeof(uint16_t);
  const size_t ws_need = bfA + bfB + (size_t)(M + N) * sizeof(float);

  if (d_ws != nullptr && ws_size >= ws_need) {
    uint16_t* Abf = (uint16_t*)d_ws;
    uint16_t* Bbf = (uint16_t*)((char*)d_ws + bfA);
    float* fsq = (float*)((char*)d_ws + bfA + bfB);
    float* psq = fsq + M;
    const int rows = M + N;
    prep_kernel<<<dim3((rows + 3) / 4), dim3(256), 0, stream>>>(
        feat, prot, Abf, Bbf, fsq, psq, M, N);
    dim3 grid((N + BN2 - 1) / BN2, (M + BM2 - 1) / BM2);
    gemm_kernel<<<grid, dim3(512), 0, stream>>>(Abf, Bbf, fsq, psq, out, M, N);
  } else {
    dim3 grid((N + BN - 1) / BN, (M + BM - 1) / BM);
    dist_mfma_kernel<<<grid, dim3(256), 0, stream>>>(feat, prot, out, M, N);
  }
}